// Round 15
// baseline (206.896 us; speedup 1.0000x reference)
//
#include <hip/hip_runtime.h>
#include <math.h>

// ---- variant toggles (validated in R6) ----
#define BLAS_FMA 1
#define SYR2_VARIANT 0

#define DEV static __device__ __forceinline__

// f32 IEEE ops, opaque to fp-contract
DEV float fA(float a, float b){ return __fadd_rn(a,b); }
DEV float fSb(float a, float b){ return __fsub_rn(a,b); }
DEV float fM(float a, float b){ return __fmul_rn(a,b); }
DEV float fDv(float a, float b){ return __fdiv_rn(a,b); }
DEV float fQ(float a){ return __fsqrt_rn(a); }
DEV float fF(float a, float b, float c){ return __builtin_fmaf(a,b,c); }
DEV float fSGN(float a, float b){ return copysignf(a,b); }

DEV float slapy2f(float x, float y){
  float xa=fabsf(x), ya=fabsf(y);
  float w=fmaxf(xa,ya), z=fminf(xa,ya);
  if (z==0.0f) return w;
  float t=fDv(z,w);
  return fM(w, fQ(fA(1.0f, fM(t,t))));
}

// LAPACK >=3.10 slartg (f32)
DEV void slartgf(float f, float g, float* c, float* s, float* r){
  const float safmin=1.17549435e-38f;
  const float safmax=8.50705917e+37f;
  const float rtmin=1.08420217e-19f;
  const float rtmax=6.52169543e+18f;
  float f1=fabsf(f), g1=fabsf(g);
  if (g==0.0f){ *c=1.0f; *s=0.0f; *r=f; }
  else if (f==0.0f){ *c=0.0f; *s=fSGN(1.0f,g); *r=g1; }
  else {
    if (f1>rtmin && f1<rtmax && g1>rtmin && g1<rtmax){
      float d=fQ(fA(fM(f,f), fM(g,g)));
      *c=fDv(f1,d);
      *r=fSGN(d,f);
      *s=fDv(g,*r);
    } else {
      float u=fminf(safmax, fmaxf(safmin, fmaxf(f1,g1)));
      float fs=fDv(f,u), gs=fDv(g,u);
      float d=fQ(fA(fM(fs,fs), fM(gs,gs)));
      *c=fDv(fabsf(fs), d);
      *r=fSGN(d,f);
      *s=fDv(gs,*r);
      *r=fM(*r,u);
    }
  }
}

DEV void slaev2f(float a, float b, float c, float* rt1, float* rt2, float* cs1, float* sn1){
  float sm=fA(a,c);
  float df=fSb(a,c);
  float adf=fabsf(df);
  float tb=fA(b,b);
  float ab=fabsf(tb);
  float acmx, acmn;
  if (fabsf(a)>fabsf(c)){ acmx=a; acmn=c; } else { acmx=c; acmn=a; }
  float rt;
  if (adf>ab){ float t=fDv(ab,adf); rt=fM(adf, fQ(fA(1.0f, fM(t,t)))); }
  else if (adf<ab){ float t=fDv(adf,ab); rt=fM(ab, fQ(fA(1.0f, fM(t,t)))); }
  else { rt=fM(ab, fQ(2.0f)); }
  int sgn1;
  if (sm<0.0f){
    *rt1=fM(0.5f, fSb(sm,rt)); sgn1=-1;
    *rt2=fSb(fM(fDv(acmx,*rt1),acmn), fM(fDv(b,*rt1),b));
  } else if (sm>0.0f){
    *rt1=fM(0.5f, fA(sm,rt)); sgn1=1;
    *rt2=fSb(fM(fDv(acmx,*rt1),acmn), fM(fDv(b,*rt1),b));
  } else {
    *rt1=fM(0.5f,rt); *rt2=fM(-0.5f,rt); sgn1=1;
  }
  float cs; int sgn2;
  if (df>=0.0f){ cs=fA(df,rt); sgn2=1; } else { cs=fSb(df,rt); sgn2=-1; }
  float acs=fabsf(cs);
  if (acs>ab){
    float ct=fDv(-tb,cs);
    *sn1=fDv(1.0f, fQ(fA(1.0f, fM(ct,ct))));
    *cs1=fM(ct,*sn1);
  } else {
    if (ab==0.0f){ *cs1=1.0f; *sn1=0.0f; }
    else {
      float tn=fDv(-cs,tb);
      *cs1=fDv(1.0f, fQ(fA(1.0f, fM(tn,tn))));
      *sn1=fM(tn,*cs1);
    }
  }
  if (sgn1==sgn2){ float tn=*cs1; *cs1=-(*sn1); *sn1=tn; }
}

// f32 ssyevd(n=3,'L','V') emulating scipy-openblas32 (R6-validated, byte-for-byte)
DEV void eig3_smallest(float a00, float a10, float a20, float a11, float a21, float a22,
                       float* vout){
  const float RMIN=3.13916472e-16f;
  const float RMAX=3.18559313e+15f;
  float anrm=fmaxf(fabsf(a00), fmaxf(fabsf(a10), fmaxf(fabsf(a20),
             fmaxf(fabsf(a11), fmaxf(fabsf(a21), fabsf(a22))))));
  if (anrm>0.0f && anrm<RMIN){
    float sig=fDv(RMIN,anrm);
    a00=fM(a00,sig); a10=fM(a10,sig); a20=fM(a20,sig);
    a11=fM(a11,sig); a21=fM(a21,sig); a22=fM(a22,sig);
  } else if (anrm>RMAX){
    float sig=fDv(RMAX,anrm);
    a00=fM(a00,sig); a10=fM(a10,sig); a20=fM(a20,sig);
    a11=fM(a11,sig); a21=fM(a21,sig); a22=fM(a22,sig);
  }
  float d[3], e[2];
  float tau1=0.0f, hv2=0.0f;
  {
    float xnorm=fabsf(a20);
    if (xnorm==0.0f){
      tau1=0.0f;
      d[0]=a00; d[1]=a11; d[2]=a22;
      e[0]=a10; e[1]=a21;
    } else {
      float alpha=a10;
      float beta=-fSGN(slapy2f(alpha,xnorm), alpha);
      tau1=fDv(fSb(beta,alpha), beta);
      float rs=fDv(1.0f, fSb(alpha,beta));
      hv2=fM(a20, rs);
      float t2a=fM(a21, hv2);
#if BLAS_FMA
      float w1=fF(tau1, t2a, fM(tau1, a11));
      float w2=fF(fM(tau1,hv2), a22, fM(tau1, a21));
      float sd=fF(hv2, w2, w1);
#else
      float w1=fA(fM(tau1,a11), fM(tau1,t2a));
      float w2=fA(fM(tau1,a21), fM(fM(tau1,hv2),a22));
      float sd=fA(w1, fM(w2,hv2));
#endif
      float al2=fM(fM(-0.5f,tau1), sd);
      float nw1=fA(w1, al2);
#if BLAS_FMA
      float nw2=fF(al2, hv2, w2);
#else
      float nw2=fA(w2, fM(al2,hv2));
#endif
      w1=nw1; w2=nw2;
      float b11, b21, b22;
#if SYR2_VARIANT==0
      b11=fA(a11, fM(-2.0f, w1));
      b21=fA(a21, fF(hv2, -w1, -w2));
      b22=fA(a22, fF(hv2, -w2, fM(w2, -hv2)));
#elif SYR2_VARIANT==1
      b11=fSb(fSb(a11, w1), w1);
      b21=fSb(fF(hv2, -w1, a21), w2);
      b22=fF(w2, -hv2, fF(hv2, -w2, a22));
#else
      b11=fA(fA(a11, -w1), -w1);
      b21=fA(fA(a21, fM(hv2,-w1)), -w2);
      b22=fA(fA(a22, fM(hv2,-w2)), fM(w2,-hv2));
#endif
      d[0]=a00; d[1]=b11; d[2]=b22;
      e[0]=beta; e[1]=b21;
    }
  }
  float z[9]={1.0f,0.0f,0.0f, 0.0f,1.0f,0.0f, 0.0f,0.0f,1.0f};
  const float EPS=5.96046448e-08f;
  const float EPS2=3.55271368e-15f;
  const float SAFMIN=1.17549435e-38f;
  const float SSFMAX=3.07445735e+18f;
  const float SSFMIN=3.05175781e-05f;
  int l1=1, jtot=0; const int nmaxit=90;
  bool skip_sort=false;
  while (l1<=3){
    if (l1>1) e[l1-2]=0.0f;
    int m=3;
    for (int mm=l1; mm<=2; ++mm){
      float tst=fabsf(e[mm-1]);
      if (tst==0.0f){ m=mm; break; }
      if (tst<=fM(fM(fQ(fabsf(d[mm-1])), fQ(fabsf(d[mm]))), EPS)){ e[mm-1]=0.0f; m=mm; break; }
    }
    int l=l1, lsv=l, lend=m, lendsv=m;
    l1=m+1;
    if (lend==l) continue;
    float anorm=fabsf(d[lend-1]);
    for (int i=l; i<=lend-1; ++i){ anorm=fmaxf(anorm,fabsf(d[i-1])); anorm=fmaxf(anorm,fabsf(e[i-1])); }
    if (anorm==0.0f) continue;
    int iscale=0;
    if (anorm>SSFMAX){
      iscale=1; float mv=fDv(SSFMAX,anorm);
      for (int i=l;i<=lend;++i) d[i-1]=fM(d[i-1],mv);
      for (int i=l;i<=lend-1;++i) e[i-1]=fM(e[i-1],mv);
    } else if (anorm<SSFMIN){
      iscale=2; float mv=fDv(SSFMIN,anorm);
      for (int i=l;i<=lend;++i) d[i-1]=fM(d[i-1],mv);
      for (int i=l;i<=lend-1;++i) e[i-1]=fM(e[i-1],mv);
    }
    if (fabsf(d[lend-1])<fabsf(d[l-1])){ lend=lsv; l=lendsv; }
    if (lend>l){
      for (;;){
        int M=lend;
        if (l!=lend){
          for (int mm=l; mm<=lend-1; ++mm){
            float ee=fabsf(e[mm-1]);
            float tst=fM(ee,ee);
            if (tst<=fA(fM(fM(EPS2,fabsf(d[mm-1])), fabsf(d[mm])), SAFMIN)){ M=mm; break; }
          }
        }
        if (M<lend) e[M-1]=0.0f;
        float p=d[l-1];
        if (M==l){
          l+=1;
          if (l<=lend) continue; else break;
        }
        if (M==l+1){
          float rt1,rt2,cc,ss;
          slaev2f(d[l-1], e[l-1], d[l], &rt1,&rt2,&cc,&ss);
          for (int i=0;i<3;++i){
            float t=z[i+3*l];
            z[i+3*l]    =fSb(fM(cc,t), fM(ss,z[i+3*(l-1)]));
            z[i+3*(l-1)]=fA (fM(ss,t), fM(cc,z[i+3*(l-1)]));
          }
          d[l-1]=rt1; d[l]=rt2; e[l-1]=0.0f; l+=2;
          if (l<=lend) continue; else break;
        }
        if (jtot==nmaxit) break;
        ++jtot;
        float g=fDv(fSb(d[l],p), fM(2.0f,e[l-1]));
        float r=slapy2f(g,1.0f);
        g=fA(fSb(d[M-1],p), fDv(e[l-1], fA(g, fSGN(r,g))));
        float s=1.0f, c=1.0f; p=0.0f;
        float cst[2], sst[2];
        for (int i=M-1; i>=l; --i){
          float f=fM(s,e[i-1]);
          float bb=fM(c,e[i-1]);
          slartgf(g,f,&c,&s,&r);
          if (i!=M-1) e[i]=r;
          g=fSb(d[i],p);
          r=fA(fM(fSb(d[i-1],g),s), fM(fM(2.0f,c),bb));
          p=fM(s,r);
          d[i]=fA(g,p);
          g=fSb(fM(c,r),bb);
          cst[i-l]=c; sst[i-l]=-s;
        }
        int nr=M-l;
        for (int j=nr; j>=1; --j){
          float ct=cst[j-1], st=sst[j-1];
          if (ct!=1.0f || st!=0.0f){
            int c0=(l-1)+(j-1);
            for (int i=0;i<3;++i){
              float t=z[i+3*(c0+1)];
              z[i+3*(c0+1)]=fSb(fM(ct,t), fM(st,z[i+3*c0]));
              z[i+3*c0]    =fA (fM(st,t), fM(ct,z[i+3*c0]));
            }
          }
        }
        d[l-1]=fSb(d[l-1],p);
        e[l-1]=g;
      }
    } else {
      for (;;){
        int M=lend;
        if (l!=lend){
          for (int mm=l; mm>=lend+1; --mm){
            float ee=fabsf(e[mm-2]);
            float tst=fM(ee,ee);
            if (tst<=fA(fM(fM(EPS2,fabsf(d[mm-1])), fabsf(d[mm-2])), SAFMIN)){ M=mm; break; }
          }
        }
        if (M>lend) e[M-2]=0.0f;
        float p=d[l-1];
        if (M==l){
          l-=1;
          if (l>=lend) continue; else break;
        }
        if (M==l-1){
          float rt1,rt2,cc,ss;
          slaev2f(d[l-2], e[l-2], d[l-1], &rt1,&rt2,&cc,&ss);
          for (int i=0;i<3;++i){
            float t=z[i+3*(l-1)];
            z[i+3*(l-1)]=fSb(fM(cc,t), fM(ss,z[i+3*(l-2)]));
            z[i+3*(l-2)]=fA (fM(ss,t), fM(cc,z[i+3*(l-2)]));
          }
          d[l-2]=rt1; d[l-1]=rt2; e[l-2]=0.0f; l-=2;
          if (l>=lend) continue; else break;
        }
        if (jtot==nmaxit) break;
        ++jtot;
        float g=fDv(fSb(d[l-2],p), fM(2.0f,e[l-2]));
        float r=slapy2f(g,1.0f);
        g=fA(fSb(d[M-1],p), fDv(e[l-2], fA(g, fSGN(r,g))));
        float s=1.0f, c=1.0f; p=0.0f;
        float cst[2], sst[2];
        for (int i=M; i<=l-1; ++i){
          float f=fM(s,e[i-1]);
          float bb=fM(c,e[i-1]);
          slartgf(g,f,&c,&s,&r);
          if (i!=M) e[i-2]=r;
          g=fSb(d[i-1],p);
          r=fA(fM(fSb(d[i],g),s), fM(fM(2.0f,c),bb));
          p=fM(s,r);
          d[i-1]=fA(g,p);
          g=fSb(fM(c,r),bb);
          cst[i-M]=c; sst[i-M]=s;
        }
        int nr=l-M;
        for (int j=1; j<=nr; ++j){
          float ct=cst[j-1], st=sst[j-1];
          if (ct!=1.0f || st!=0.0f){
            int c0=(M-1)+(j-1);
            for (int i=0;i<3;++i){
              float t=z[i+3*(c0+1)];
              z[i+3*(c0+1)]=fSb(fM(ct,t), fM(st,z[i+3*c0]));
              z[i+3*c0]    =fA(fM(st,t), fM(ct,z[i+3*c0]));
            }
          }
        }
        d[l-1]=fSb(d[l-1],p);
        e[l-2]=g;
      }
    }
    if (iscale==1){
      float mv=fDv(anorm,SSFMAX);
      for (int i=lsv;i<=lendsv;++i) d[i-1]=fM(d[i-1],mv);
      for (int i=lsv;i<=lendsv-1;++i) e[i-1]=fM(e[i-1],mv);
    } else if (iscale==2){
      float mv=fDv(anorm,SSFMIN);
      for (int i=lsv;i<=lendsv;++i) d[i-1]=fM(d[i-1],mv);
      for (int i=lsv;i<=lendsv-1;++i) e[i-1]=fM(e[i-1],mv);
    }
    if (jtot>=nmaxit){ skip_sort=true; break; }
  }
  if (!skip_sort){
    for (int ii=2; ii<=3; ++ii){
      int i=ii-1, k=i; float p=d[i-1];
      for (int j=ii; j<=3; ++j) if (d[j-1]<p){ k=j; p=d[j-1]; }
      if (k!=i){
        d[k-1]=d[i-1]; d[i-1]=p;
        for (int row=0; row<3; ++row){
          float t=z[row+3*(i-1)]; z[row+3*(i-1)]=z[row+3*(k-1)]; z[row+3*(k-1)]=t;
        }
      }
    }
  }
  float z0=z[0], z1=z[1], z2=z[2];
  if (tau1!=0.0f){
#if BLAS_FMA
    float wv=fF(hv2, z2, z1);
    float t2=fM(-tau1, wv);
    z1=fA(z1, t2);
    z2=fF(t2, hv2, z2);
#else
    float wv=fA(z1, fM(z2,hv2));
    float t2=fM(-tau1, wv);
    z1=fA(z1, t2);
    z2=fA(z2, fM(hv2,t2));
#endif
  }
  vout[0]=z0; vout[1]=z1; vout[2]=z2;
}

struct KP {
  const float* x; const float* rs; const float* rl;
  const float *w1,*b1,*g1,*be1,*m1,*v1;
  const float *w2,*b2,*g2,*be2,*m2,*v2;
  const float *w3,*b3,*g3,*be3,*m3,*v3;
  const float *w4,*b4,*g4,*be4,*m4,*v4;
  float* out;
};

// ws region A: per-point idx record, 128 u16 = 256 B.
// [0..63]=idxL, [64..95]=idxS, [96]=cl, [97]=cs.
#define WS_STRIDE 128

// ---- Kernel 1: wave-per-point ballot scan; indices buffered in LDS,
// record written with ONE coalesced 49-dword store (no in-loop global stores).
__global__ __launch_bounds__(64) void scan_kernel(const float* __restrict__ x,
                                                  const float* __restrict__ rsp,
                                                  const float* __restrict__ rlp,
                                                  unsigned short* __restrict__ ws){
  __shared__ unsigned short sIdx[128];    // [0..63]=L, [64..95]=S, [96]=cl, [97]=cs
  const int lane=threadIdx.x;
  const int pt=blockIdx.x;
  const int b=pt>>12, n=pt&4095;
  const float* P=x+(size_t)b*(4096*3);
  const double rds=rint((double)rsp[0]*1e7)/1e7;
  const double rdl=rint((double)rlp[0]*1e7)/1e7;
  const float rr_s=(float)(rds*rds);
  const float rr_l=(float)(rdl*rdl);
  const float px=P[3*n], py=P[3*n+1], pz=P[3*n+2];
  const float sqn=fA(fA(fM(px,px),fM(py,py)),fM(pz,pz));
  int cs=0, cl=0;
  for (int c=0;c<64;++c){
    int j=c*64+lane;
    float qx=P[3*j], qy=P[3*j+1], qz=P[3*j+2];
    float sqj=fA(fA(fM(qx,qx),fM(qy,qy)),fM(qz,qz));
    float dot=fA(fA(fM(px,qx),fM(py,qy)),fM(pz,qz));
    float d2=fSb(fA(sqn,sqj), fM(2.0f,dot));
    bool pl=!(d2>rr_l);
    bool ps=!(d2>rr_s);
    unsigned long long bl=__ballot(pl);
    unsigned long long bs=__ballot(ps);
    unsigned long long ltm=(1ull<<lane)-1ull;
    int posl=cl+__popcll(bl&ltm);
    int poss=cs+__popcll(bs&ltm);
    if (pl&&posl<64) sIdx[posl]=(unsigned short)j;
    if (ps&&poss<32) sIdx[64+poss]=(unsigned short)j;
    cl+=__popcll(bl); if(cl>64) cl=64;
    cs+=__popcll(bs); if(cs>32) cs=32;
    if (cs>=32&&cl>=64) break;          // wave-uniform
  }
  if (lane==0){ sIdx[96]=(unsigned short)cl; sIdx[97]=(unsigned short)cs; }
  __syncthreads();
  unsigned int* wd=(unsigned int*)(ws+(size_t)pt*WS_STRIDE);
  const unsigned int* sd=(const unsigned int*)sIdx;
  if (lane<49) wd[lane]=sd[lane];       // coalesced 196-B record store
}

// ---- Kernel 2: fused moments + eig + MLP. Block = 1 wave, 16 points.
// Moments: R13-bit-validated chain decomposition, one chain per lane
// (96 sum chains in 2 passes, 192 cov chains in 3 passes), coords gathered
// from L2-hot batch; exact per-chain op order of R6..R14 => bit-identical.
// Eig: g=2 redundancy (R12-validated). MLP: lanes 0..15.
__global__ __launch_bounds__(64) void eigmlp_kernel(KP kp, const unsigned short* __restrict__ ws){
  __shared__ unsigned int sWu[16*65];     // 16 records x 64 dwords, row-padded
  __shared__ float sSum[96];
  __shared__ float sCov[192];
  __shared__ float sN[32][3];
  const int lane=threadIdx.x;
  const int base=blockIdx.x*16;           // 16 consecutive points, same batch
  const int b=base>>12;
  const float* X=kp.x+(size_t)b*(4096*3);
  {
    const unsigned int* wsrc=(const unsigned int*)(ws+(size_t)base*WS_STRIDE);
    for (int i=lane;i<16*64;i+=64){
      int row=i>>6, col=i&63;
      sWu[row*65+col]=wsrc[i];
    }
  }
  __syncthreads();
  const unsigned short* sW16=(const unsigned short*)sWu;

  // ---- sum chains: 96 = 16 pts x {small xyz, large xyz} ----
  for (int pass=0; pass<2; ++pass){
    int c=pass*64+lane;
    if (c<96){
      int pt=c/6, rem=c-6*pt;
      int g=rem/3, ci=rem-3*g;            // g=0 small, 1 large (R7 order)
      const int r130=pt*130;
      int cnt=g?(int)sW16[r130+96]:(int)sW16[r130+97];
      int lim=g?64:32;
      int j0 =g?(int)sW16[r130+0]:(int)sW16[r130+64];
      float acc=0.0f;
#pragma unroll 16
      for (int k=0;k<64;++k){
        if (k>=lim) break;
        int idx=(k<cnt)?(g?(int)sW16[r130+k]:(int)sW16[r130+64+k]):j0;
        acc=fA(acc, X[3*idx+ci]);
      }
      sSum[c]=acc;
    }
  }
  __syncthreads();

  // ---- cov chains: 192 = 16 pts x 12 (R13-validated a/bi maps) ----
  for (int pass=0; pass<3; ++pass){
    int c=pass*64+lane;                   // 0..191 exactly
    int pt=c/12, ce=c-12*pt;
    int g=ce/6, cc=ce-6*g;
    int a =(cc<3)?cc:((cc==5)?2:(cc-2));  // {0,1,2,1,2,2}
    int bi=(cc<3)?0 :((cc==5)?2:1);       // {0,0,0,1,1,2}
    const int r130=pt*130;
    int cnt=g?(int)sW16[r130+96]:(int)sW16[r130+97];
    int lim=g?64:32;
    int j0 =g?(int)sW16[r130+0]:(int)sW16[r130+64];
    float denom=g?64.0f:32.0f;
    float mA=fDv(sSum[pt*6+g*3+a], denom);
    float mB=fDv(sSum[pt*6+g*3+bi], denom);
    float acc=0.0f;
#pragma unroll 16
    for (int k=0;k<64;++k){
      if (k>=lim) break;
      int idx=(k<cnt)?(g?(int)sW16[r130+k]:(int)sW16[r130+64+k]):j0;
      float va=fSb(X[3*idx+a], mA);
      float vb=fSb(X[3*idx+bi], mB);
      acc=fA(acc, fM(va,vb));
    }
    sCov[c]=acc;                          // layout: pt*12 + (g*6+cc) == R12 covB
  }
  __syncthreads();

  // ---- eig: 2-lane redundancy, 32 tasks (R12-validated) ----
  {
    const int g2=lane>>1;                 // task 0..31
    const int p=g2>>1, which=g2&1;
    const float* cb=&sCov[p*12+which*6];
    float v[3];
    eig3_smallest(cb[0],cb[1],cb[2],cb[3],cb[4],cb[5],v);
    if ((lane&1)==0){ sN[g2][0]=v[0]; sN[g2][1]=v[1]; sN[g2][2]=v[2]; }
  }
  __syncthreads();

  if (lane<16){
    const int pt=base+lane;
    const float* sn=sN[2*lane];
    const float* ln=sN[2*lane+1];
    float dx=fM(fSb(sn[0],ln[0]),0.5f);
    float dy=fM(fSb(sn[1],ln[1]),0.5f);
    float dz=fM(fSb(sn[2],ln[2]),0.5f);
    float curv=fQ(fA(fA(fM(dx,dx),fM(dy,dy)),fM(dz,dz)));

    float h1[16];
#pragma unroll
    for (int j=0;j<16;++j){
      float a0=fA(fM(kp.w1[j],curv), kp.b1[j]);
      a0=fA(fM(fDv(fSb(a0,kp.m1[j]), fQ(fA(kp.v1[j],1e-5f))), kp.g1[j]), kp.be1[j]);
      h1[j]=fmaxf(a0,0.0f);
    }
    float h2[32];
#pragma unroll
    for (int j=0;j<32;++j){
      float a0=0.0f;
#pragma unroll
      for (int k=0;k<16;++k) a0=fF(h1[k], kp.w2[j*16+k], a0);
      a0=fA(a0, kp.b2[j]);
      a0=fA(fM(fDv(fSb(a0,kp.m2[j]), fQ(fA(kp.v2[j],1e-5f))), kp.g2[j]), kp.be2[j]);
      h2[j]=fmaxf(a0,0.0f);
    }
    float h3[16];
#pragma unroll
    for (int j=0;j<16;++j){
      float a0=0.0f;
#pragma unroll
      for (int k=0;k<32;++k) a0=fF(h2[k], kp.w3[j*32+k], a0);
      a0=fA(a0, kp.b3[j]);
      a0=fA(fM(fDv(fSb(a0,kp.m3[j]), fQ(fA(kp.v3[j],1e-5f))), kp.g3[j]), kp.be3[j]);
      h3[j]=fmaxf(a0,0.0f);
    }
    float o=0.0f;
#pragma unroll
    for (int k=0;k<16;++k) o=fF(h3[k], kp.w4[k], o);
    o=fA(o, kp.b4[0]);
    o=fA(fM(fDv(fSb(o,kp.m4[0]), fQ(fA(kp.v4[0],1e-5f))), kp.g4[0]), kp.be4[0]);
    kp.out[pt]=o;
  }
}

// ---- Fallback: R8 monolithic kernel (used only if ws is too small) ----
__global__ __launch_bounds__(256) void freq_kernel(KP kp){
  __shared__ float sP[4096*3];
  __shared__ float sSq[4096];
  __shared__ unsigned short sIdxL[64][66];
  __shared__ unsigned short sIdxS[64][34];
  __shared__ unsigned char sCntL[64], sCntS[64];
  const int tid=threadIdx.x;
  const int lane=tid&63, wid=tid>>6;
  const int b=blockIdx.x>>6;
  const int n0=(blockIdx.x&63)*64;
  const float* P=kp.x+(size_t)b*(4096*3);
  for (int i=tid;i<4096*3;i+=256) sP[i]=P[i];
  for (int j=tid;j<4096;j+=256){
    float qx=P[3*j],qy=P[3*j+1],qz=P[3*j+2];
    sSq[j]=fA(fA(fM(qx,qx),fM(qy,qy)),fM(qz,qz));
  }
  __syncthreads();
  const double rds=rint((double)kp.rs[0]*1e7)/1e7;
  const double rdl=rint((double)kp.rl[0]*1e7)/1e7;
  const float rr_s=(float)(rds*rds);
  const float rr_l=(float)(rdl*rdl);
  for (int pi=0; pi<16; ++pi){
    const int pl_i=wid*16+pi;
    const int n=n0+pl_i;
    const float px=sP[3*n], py=sP[3*n+1], pz=sP[3*n+2];
    const float sqn=sSq[n];
    int cs=0, cl=0;
    for (int c=0;c<64;++c){
      int j=c*64+lane;
      float dot=fA(fA(fM(px,sP[3*j]),fM(py,sP[3*j+1])),fM(pz,sP[3*j+2]));
      float d2=fSb(fA(sqn,sSq[j]), fM(2.0f,dot));
      bool pl_=!(d2>rr_l);
      bool ps_=!(d2>rr_s);
      unsigned long long bl=__ballot(pl_);
      unsigned long long bs=__ballot(ps_);
      unsigned long long ltm=(1ull<<lane)-1ull;
      int posl=cl+__popcll(bl&ltm);
      int poss=cs+__popcll(bs&ltm);
      if (pl_&&posl<64) sIdxL[pl_i][posl]=(unsigned short)j;
      if (ps_&&poss<32) sIdxS[pl_i][poss]=(unsigned short)j;
      cl+=__popcll(bl); if(cl>64) cl=64;
      cs+=__popcll(bs); if(cs>32) cs=32;
      if (cs>=32&&cl>=64) break;
    }
    if (lane==0){ sCntL[pl_i]=(unsigned char)cl; sCntS[pl_i]=(unsigned char)cs; }
  }
  __syncthreads();
  if (lane<16){
    const int pl_i=wid*16+lane;
    const int ptg=blockIdx.x*64+pl_i;
    const int csn=sCntS[pl_i], cln=sCntL[pl_i];
    const int j0s=sIdxS[pl_i][0], j0l=sIdxL[pl_i][0];
    float ssx=0.0f,ssy=0.0f,ssz=0.0f, slx=0.0f,sly=0.0f,slz=0.0f;
    for (int k=0;k<32;++k){
      int idx=(k<csn)?(int)sIdxS[pl_i][k]:j0s;
      ssx=fA(ssx,sP[3*idx]); ssy=fA(ssy,sP[3*idx+1]); ssz=fA(ssz,sP[3*idx+2]);
    }
    for (int k=0;k<64;++k){
      int idx=(k<cln)?(int)sIdxL[pl_i][k]:j0l;
      slx=fA(slx,sP[3*idx]); sly=fA(sly,sP[3*idx+1]); slz=fA(slz,sP[3*idx+2]);
    }
    const float msx=fDv(ssx,32.0f), msy=fDv(ssy,32.0f), msz=fDv(ssz,32.0f);
    const float mlx=fDv(slx,64.0f), mly=fDv(sly,64.0f), mlz=fDv(slz,64.0f);
    float sc0=0,sc1=0,sc2=0,sc3=0,sc4=0,sc5=0;
    for (int k=0;k<32;++k){
      int idx=(k<csn)?(int)sIdxS[pl_i][k]:j0s;
      float cx=fSb(sP[3*idx],msx), cy=fSb(sP[3*idx+1],msy), cz=fSb(sP[3*idx+2],msz);
      sc0=fA(sc0,fM(cx,cx)); sc1=fA(sc1,fM(cy,cx)); sc2=fA(sc2,fM(cz,cx));
      sc3=fA(sc3,fM(cy,cy)); sc4=fA(sc4,fM(cz,cy)); sc5=fA(sc5,fM(cz,cz));
    }
    float lc0=0,lc1=0,lc2=0,lc3=0,lc4=0,lc5=0;
    for (int k=0;k<64;++k){
      int idx=(k<cln)?(int)sIdxL[pl_i][k]:j0l;
      float cx=fSb(sP[3*idx],mlx), cy=fSb(sP[3*idx+1],mly), cz=fSb(sP[3*idx+2],mlz);
      lc0=fA(lc0,fM(cx,cx)); lc1=fA(lc1,fM(cy,cx)); lc2=fA(lc2,fM(cz,cx));
      lc3=fA(lc3,fM(cy,cy)); lc4=fA(lc4,fM(cz,cy)); lc5=fA(lc5,fM(cz,cz));
    }
    float snv[3], lnv[3];
    eig3_smallest(sc0,sc1,sc2,sc3,sc4,sc5, snv);
    eig3_smallest(lc0,lc1,lc2,lc3,lc4,lc5, lnv);
    float dx=fM(fSb(snv[0],lnv[0]),0.5f);
    float dy=fM(fSb(snv[1],lnv[1]),0.5f);
    float dz=fM(fSb(snv[2],lnv[2]),0.5f);
    float curv=fQ(fA(fA(fM(dx,dx),fM(dy,dy)),fM(dz,dz)));
    float h1[16];
#pragma unroll
    for (int j=0;j<16;++j){
      float a0=fA(fM(kp.w1[j],curv), kp.b1[j]);
      a0=fA(fM(fDv(fSb(a0,kp.m1[j]), fQ(fA(kp.v1[j],1e-5f))), kp.g1[j]), kp.be1[j]);
      h1[j]=fmaxf(a0,0.0f);
    }
    float h2[32];
#pragma unroll
    for (int j=0;j<32;++j){
      float a0=0.0f;
#pragma unroll
      for (int k=0;k<16;++k) a0=fF(h1[k], kp.w2[j*16+k], a0);
      a0=fA(a0, kp.b2[j]);
      a0=fA(fM(fDv(fSb(a0,kp.m2[j]), fQ(fA(kp.v2[j],1e-5f))), kp.g2[j]), kp.be2[j]);
      h2[j]=fmaxf(a0,0.0f);
    }
    float h3[16];
#pragma unroll
    for (int j=0;j<16;++j){
      float a0=0.0f;
#pragma unroll
      for (int k=0;k<32;++k) a0=fF(h2[k], kp.w3[j*32+k], a0);
      a0=fA(a0, kp.b3[j]);
      a0=fA(fM(fDv(fSb(a0,kp.m3[j]), fQ(fA(kp.v3[j],1e-5f))), kp.g3[j]), kp.be3[j]);
      h3[j]=fmaxf(a0,0.0f);
    }
    float o=0.0f;
#pragma unroll
    for (int k=0;k<16;++k) o=fF(h3[k], kp.w4[k], o);
    o=fA(o, kp.b4[0]);
    o=fA(fM(fDv(fSb(o,kp.m4[0]), fQ(fA(kp.v4[0],1e-5f))), kp.g4[0]), kp.be4[0]);
    kp.out[ptg]=o;
  }
}

extern "C" void kernel_launch(void* const* d_in, const int* in_sizes, int n_in,
                              void* d_out, int out_size, void* d_ws, size_t ws_size,
                              hipStream_t stream){
  (void)n_in; (void)out_size;
  KP kp;
  kp.x  =(const float*)d_in[0];
  kp.rs =(const float*)d_in[1];
  kp.rl =(const float*)d_in[2];
  kp.w1 =(const float*)d_in[3];  kp.b1 =(const float*)d_in[4];  kp.g1 =(const float*)d_in[5];
  kp.be1=(const float*)d_in[6];  kp.m1 =(const float*)d_in[7];  kp.v1 =(const float*)d_in[8];
  kp.w2 =(const float*)d_in[9];  kp.b2 =(const float*)d_in[10]; kp.g2 =(const float*)d_in[11];
  kp.be2=(const float*)d_in[12]; kp.m2 =(const float*)d_in[13]; kp.v2 =(const float*)d_in[14];
  kp.w3 =(const float*)d_in[15]; kp.b3 =(const float*)d_in[16]; kp.g3 =(const float*)d_in[17];
  kp.be3=(const float*)d_in[18]; kp.m3 =(const float*)d_in[19]; kp.v3 =(const float*)d_in[20];
  kp.w4 =(const float*)d_in[21]; kp.b4 =(const float*)d_in[22]; kp.g4 =(const float*)d_in[23];
  kp.be4=(const float*)d_in[24]; kp.m4 =(const float*)d_in[25]; kp.v4 =(const float*)d_in[26];
  kp.out=(float*)d_out;
  const int BN=in_sizes[0]/3;               // B*N points
  const size_t ws_need=(size_t)BN*256;      // idx records only
  if (ws_size>=ws_need){
    unsigned short* wsA=(unsigned short*)d_ws;
    scan_kernel<<<BN, 64, 0, stream>>>(kp.x, kp.rs, kp.rl, wsA);
    eigmlp_kernel<<<BN/16, 64, 0, stream>>>(kp, wsA);
  } else {
    freq_kernel<<<BN/64, 256, 0, stream>>>(kp);
  }
}

// Round 16
// 196.034 us; speedup vs baseline: 1.0554x; 1.0554x over previous
//
#include <hip/hip_runtime.h>
#include <math.h>

// ---- variant toggles (validated in R6) ----
#define BLAS_FMA 1
#define SYR2_VARIANT 0

#define DEV static __device__ __forceinline__

// f32 IEEE ops, opaque to fp-contract
DEV float fA(float a, float b){ return __fadd_rn(a,b); }
DEV float fSb(float a, float b){ return __fsub_rn(a,b); }
DEV float fM(float a, float b){ return __fmul_rn(a,b); }
DEV float fDv(float a, float b){ return __fdiv_rn(a,b); }
DEV float fQ(float a){ return __fsqrt_rn(a); }
DEV float fF(float a, float b, float c){ return __builtin_fmaf(a,b,c); }
DEV float fSGN(float a, float b){ return copysignf(a,b); }

DEV float slapy2f(float x, float y){
  float xa=fabsf(x), ya=fabsf(y);
  float w=fmaxf(xa,ya), z=fminf(xa,ya);
  if (z==0.0f) return w;
  float t=fDv(z,w);
  return fM(w, fQ(fA(1.0f, fM(t,t))));
}

// LAPACK >=3.10 slartg (f32)
DEV void slartgf(float f, float g, float* c, float* s, float* r){
  const float safmin=1.17549435e-38f;
  const float safmax=8.50705917e+37f;
  const float rtmin=1.08420217e-19f;
  const float rtmax=6.52169543e+18f;
  float f1=fabsf(f), g1=fabsf(g);
  if (g==0.0f){ *c=1.0f; *s=0.0f; *r=f; }
  else if (f==0.0f){ *c=0.0f; *s=fSGN(1.0f,g); *r=g1; }
  else {
    if (f1>rtmin && f1<rtmax && g1>rtmin && g1<rtmax){
      float d=fQ(fA(fM(f,f), fM(g,g)));
      *c=fDv(f1,d);
      *r=fSGN(d,f);
      *s=fDv(g,*r);
    } else {
      float u=fminf(safmax, fmaxf(safmin, fmaxf(f1,g1)));
      float fs=fDv(f,u), gs=fDv(g,u);
      float d=fQ(fA(fM(fs,fs), fM(gs,gs)));
      *c=fDv(fabsf(fs), d);
      *r=fSGN(d,f);
      *s=fDv(gs,*r);
      *r=fM(*r,u);
    }
  }
}

DEV void slaev2f(float a, float b, float c, float* rt1, float* rt2, float* cs1, float* sn1){
  float sm=fA(a,c);
  float df=fSb(a,c);
  float adf=fabsf(df);
  float tb=fA(b,b);
  float ab=fabsf(tb);
  float acmx, acmn;
  if (fabsf(a)>fabsf(c)){ acmx=a; acmn=c; } else { acmx=c; acmn=a; }
  float rt;
  if (adf>ab){ float t=fDv(ab,adf); rt=fM(adf, fQ(fA(1.0f, fM(t,t)))); }
  else if (adf<ab){ float t=fDv(adf,ab); rt=fM(ab, fQ(fA(1.0f, fM(t,t)))); }
  else { rt=fM(ab, fQ(2.0f)); }
  int sgn1;
  if (sm<0.0f){
    *rt1=fM(0.5f, fSb(sm,rt)); sgn1=-1;
    *rt2=fSb(fM(fDv(acmx,*rt1),acmn), fM(fDv(b,*rt1),b));
  } else if (sm>0.0f){
    *rt1=fM(0.5f, fA(sm,rt)); sgn1=1;
    *rt2=fSb(fM(fDv(acmx,*rt1),acmn), fM(fDv(b,*rt1),b));
  } else {
    *rt1=fM(0.5f,rt); *rt2=fM(-0.5f,rt); sgn1=1;
  }
  float cs; int sgn2;
  if (df>=0.0f){ cs=fA(df,rt); sgn2=1; } else { cs=fSb(df,rt); sgn2=-1; }
  float acs=fabsf(cs);
  if (acs>ab){
    float ct=fDv(-tb,cs);
    *sn1=fDv(1.0f, fQ(fA(1.0f, fM(ct,ct))));
    *cs1=fM(ct,*sn1);
  } else {
    if (ab==0.0f){ *cs1=1.0f; *sn1=0.0f; }
    else {
      float tn=fDv(-cs,tb);
      *cs1=fDv(1.0f, fQ(fA(1.0f, fM(tn,tn))));
      *sn1=fM(tn,*cs1);
    }
  }
  if (sgn1==sgn2){ float tn=*cs1; *cs1=-(*sn1); *sn1=tn; }
}

// f32 ssyevd(n=3,'L','V') emulating scipy-openblas32 (R6-validated, byte-for-byte)
DEV void eig3_smallest(float a00, float a10, float a20, float a11, float a21, float a22,
                       float* vout){
  const float RMIN=3.13916472e-16f;
  const float RMAX=3.18559313e+15f;
  float anrm=fmaxf(fabsf(a00), fmaxf(fabsf(a10), fmaxf(fabsf(a20),
             fmaxf(fabsf(a11), fmaxf(fabsf(a21), fabsf(a22))))));
  if (anrm>0.0f && anrm<RMIN){
    float sig=fDv(RMIN,anrm);
    a00=fM(a00,sig); a10=fM(a10,sig); a20=fM(a20,sig);
    a11=fM(a11,sig); a21=fM(a21,sig); a22=fM(a22,sig);
  } else if (anrm>RMAX){
    float sig=fDv(RMAX,anrm);
    a00=fM(a00,sig); a10=fM(a10,sig); a20=fM(a20,sig);
    a11=fM(a11,sig); a21=fM(a21,sig); a22=fM(a22,sig);
  }
  float d[3], e[2];
  float tau1=0.0f, hv2=0.0f;
  {
    float xnorm=fabsf(a20);
    if (xnorm==0.0f){
      tau1=0.0f;
      d[0]=a00; d[1]=a11; d[2]=a22;
      e[0]=a10; e[1]=a21;
    } else {
      float alpha=a10;
      float beta=-fSGN(slapy2f(alpha,xnorm), alpha);
      tau1=fDv(fSb(beta,alpha), beta);
      float rs=fDv(1.0f, fSb(alpha,beta));
      hv2=fM(a20, rs);
      float t2a=fM(a21, hv2);
#if BLAS_FMA
      float w1=fF(tau1, t2a, fM(tau1, a11));
      float w2=fF(fM(tau1,hv2), a22, fM(tau1, a21));
      float sd=fF(hv2, w2, w1);
#else
      float w1=fA(fM(tau1,a11), fM(tau1,t2a));
      float w2=fA(fM(tau1,a21), fM(fM(tau1,hv2),a22));
      float sd=fA(w1, fM(w2,hv2));
#endif
      float al2=fM(fM(-0.5f,tau1), sd);
      float nw1=fA(w1, al2);
#if BLAS_FMA
      float nw2=fF(al2, hv2, w2);
#else
      float nw2=fA(w2, fM(al2,hv2));
#endif
      w1=nw1; w2=nw2;
      float b11, b21, b22;
#if SYR2_VARIANT==0
      b11=fA(a11, fM(-2.0f, w1));
      b21=fA(a21, fF(hv2, -w1, -w2));
      b22=fA(a22, fF(hv2, -w2, fM(w2, -hv2)));
#elif SYR2_VARIANT==1
      b11=fSb(fSb(a11, w1), w1);
      b21=fSb(fF(hv2, -w1, a21), w2);
      b22=fF(w2, -hv2, fF(hv2, -w2, a22));
#else
      b11=fA(fA(a11, -w1), -w1);
      b21=fA(fA(a21, fM(hv2,-w1)), -w2);
      b22=fA(fA(a22, fM(hv2,-w2)), fM(w2,-hv2));
#endif
      d[0]=a00; d[1]=b11; d[2]=b22;
      e[0]=beta; e[1]=b21;
    }
  }
  float z[9]={1.0f,0.0f,0.0f, 0.0f,1.0f,0.0f, 0.0f,0.0f,1.0f};
  const float EPS=5.96046448e-08f;
  const float EPS2=3.55271368e-15f;
  const float SAFMIN=1.17549435e-38f;
  const float SSFMAX=3.07445735e+18f;
  const float SSFMIN=3.05175781e-05f;
  int l1=1, jtot=0; const int nmaxit=90;
  bool skip_sort=false;
  while (l1<=3){
    if (l1>1) e[l1-2]=0.0f;
    int m=3;
    for (int mm=l1; mm<=2; ++mm){
      float tst=fabsf(e[mm-1]);
      if (tst==0.0f){ m=mm; break; }
      if (tst<=fM(fM(fQ(fabsf(d[mm-1])), fQ(fabsf(d[mm]))), EPS)){ e[mm-1]=0.0f; m=mm; break; }
    }
    int l=l1, lsv=l, lend=m, lendsv=m;
    l1=m+1;
    if (lend==l) continue;
    float anorm=fabsf(d[lend-1]);
    for (int i=l; i<=lend-1; ++i){ anorm=fmaxf(anorm,fabsf(d[i-1])); anorm=fmaxf(anorm,fabsf(e[i-1])); }
    if (anorm==0.0f) continue;
    int iscale=0;
    if (anorm>SSFMAX){
      iscale=1; float mv=fDv(SSFMAX,anorm);
      for (int i=l;i<=lend;++i) d[i-1]=fM(d[i-1],mv);
      for (int i=l;i<=lend-1;++i) e[i-1]=fM(e[i-1],mv);
    } else if (anorm<SSFMIN){
      iscale=2; float mv=fDv(SSFMIN,anorm);
      for (int i=l;i<=lend;++i) d[i-1]=fM(d[i-1],mv);
      for (int i=l;i<=lend-1;++i) e[i-1]=fM(e[i-1],mv);
    }
    if (fabsf(d[lend-1])<fabsf(d[l-1])){ lend=lsv; l=lendsv; }
    if (lend>l){
      for (;;){
        int M=lend;
        if (l!=lend){
          for (int mm=l; mm<=lend-1; ++mm){
            float ee=fabsf(e[mm-1]);
            float tst=fM(ee,ee);
            if (tst<=fA(fM(fM(EPS2,fabsf(d[mm-1])), fabsf(d[mm])), SAFMIN)){ M=mm; break; }
          }
        }
        if (M<lend) e[M-1]=0.0f;
        float p=d[l-1];
        if (M==l){
          l+=1;
          if (l<=lend) continue; else break;
        }
        if (M==l+1){
          float rt1,rt2,cc,ss;
          slaev2f(d[l-1], e[l-1], d[l], &rt1,&rt2,&cc,&ss);
          for (int i=0;i<3;++i){
            float t=z[i+3*l];
            z[i+3*l]    =fSb(fM(cc,t), fM(ss,z[i+3*(l-1)]));
            z[i+3*(l-1)]=fA (fM(ss,t), fM(cc,z[i+3*(l-1)]));
          }
          d[l-1]=rt1; d[l]=rt2; e[l-1]=0.0f; l+=2;
          if (l<=lend) continue; else break;
        }
        if (jtot==nmaxit) break;
        ++jtot;
        float g=fDv(fSb(d[l],p), fM(2.0f,e[l-1]));
        float r=slapy2f(g,1.0f);
        g=fA(fSb(d[M-1],p), fDv(e[l-1], fA(g, fSGN(r,g))));
        float s=1.0f, c=1.0f; p=0.0f;
        float cst[2], sst[2];
        for (int i=M-1; i>=l; --i){
          float f=fM(s,e[i-1]);
          float bb=fM(c,e[i-1]);
          slartgf(g,f,&c,&s,&r);
          if (i!=M-1) e[i]=r;
          g=fSb(d[i],p);
          r=fA(fM(fSb(d[i-1],g),s), fM(fM(2.0f,c),bb));
          p=fM(s,r);
          d[i]=fA(g,p);
          g=fSb(fM(c,r),bb);
          cst[i-l]=c; sst[i-l]=-s;
        }
        int nr=M-l;
        for (int j=nr; j>=1; --j){
          float ct=cst[j-1], st=sst[j-1];
          if (ct!=1.0f || st!=0.0f){
            int c0=(l-1)+(j-1);
            for (int i=0;i<3;++i){
              float t=z[i+3*(c0+1)];
              z[i+3*(c0+1)]=fSb(fM(ct,t), fM(st,z[i+3*c0]));
              z[i+3*c0]    =fA (fM(st,t), fM(ct,z[i+3*c0]));
            }
          }
        }
        d[l-1]=fSb(d[l-1],p);
        e[l-1]=g;
      }
    } else {
      for (;;){
        int M=lend;
        if (l!=lend){
          for (int mm=l; mm>=lend+1; --mm){
            float ee=fabsf(e[mm-2]);
            float tst=fM(ee,ee);
            if (tst<=fA(fM(fM(EPS2,fabsf(d[mm-1])), fabsf(d[mm-2])), SAFMIN)){ M=mm; break; }
          }
        }
        if (M>lend) e[M-2]=0.0f;
        float p=d[l-1];
        if (M==l){
          l-=1;
          if (l>=lend) continue; else break;
        }
        if (M==l-1){
          float rt1,rt2,cc,ss;
          slaev2f(d[l-2], e[l-2], d[l-1], &rt1,&rt2,&cc,&ss);
          for (int i=0;i<3;++i){
            float t=z[i+3*(l-1)];
            z[i+3*(l-1)]=fSb(fM(cc,t), fM(ss,z[i+3*(l-2)]));
            z[i+3*(l-2)]=fA (fM(ss,t), fM(cc,z[i+3*(l-2)]));
          }
          d[l-2]=rt1; d[l-1]=rt2; e[l-2]=0.0f; l-=2;
          if (l>=lend) continue; else break;
        }
        if (jtot==nmaxit) break;
        ++jtot;
        float g=fDv(fSb(d[l-2],p), fM(2.0f,e[l-2]));
        float r=slapy2f(g,1.0f);
        g=fA(fSb(d[M-1],p), fDv(e[l-2], fA(g, fSGN(r,g))));
        float s=1.0f, c=1.0f; p=0.0f;
        float cst[2], sst[2];
        for (int i=M; i<=l-1; ++i){
          float f=fM(s,e[i-1]);
          float bb=fM(c,e[i-1]);
          slartgf(g,f,&c,&s,&r);
          if (i!=M) e[i-2]=r;
          g=fSb(d[i-1],p);
          r=fA(fM(fSb(d[i],g),s), fM(fM(2.0f,c),bb));
          p=fM(s,r);
          d[i-1]=fA(g,p);
          g=fSb(fM(c,r),bb);
          cst[i-M]=c; sst[i-M]=s;
        }
        int nr=l-M;
        for (int j=1; j<=nr; ++j){
          float ct=cst[j-1], st=sst[j-1];
          if (ct!=1.0f || st!=0.0f){
            int c0=(M-1)+(j-1);
            for (int i=0;i<3;++i){
              float t=z[i+3*(c0+1)];
              z[i+3*(c0+1)]=fSb(fM(ct,t), fM(st,z[i+3*c0]));
              z[i+3*c0]    =fA(fM(st,t), fM(ct,z[i+3*c0]));
            }
          }
        }
        d[l-1]=fSb(d[l-1],p);
        e[l-2]=g;
      }
    }
    if (iscale==1){
      float mv=fDv(anorm,SSFMAX);
      for (int i=lsv;i<=lendsv;++i) d[i-1]=fM(d[i-1],mv);
      for (int i=lsv;i<=lendsv-1;++i) e[i-1]=fM(e[i-1],mv);
    } else if (iscale==2){
      float mv=fDv(anorm,SSFMIN);
      for (int i=lsv;i<=lendsv;++i) d[i-1]=fM(d[i-1],mv);
      for (int i=lsv;i<=lendsv-1;++i) e[i-1]=fM(e[i-1],mv);
    }
    if (jtot>=nmaxit){ skip_sort=true; break; }
  }
  if (!skip_sort){
    for (int ii=2; ii<=3; ++ii){
      int i=ii-1, k=i; float p=d[i-1];
      for (int j=ii; j<=3; ++j) if (d[j-1]<p){ k=j; p=d[j-1]; }
      if (k!=i){
        d[k-1]=d[i-1]; d[i-1]=p;
        for (int row=0; row<3; ++row){
          float t=z[row+3*(i-1)]; z[row+3*(i-1)]=z[row+3*(k-1)]; z[row+3*(k-1)]=t;
        }
      }
    }
  }
  float z0=z[0], z1=z[1], z2=z[2];
  if (tau1!=0.0f){
#if BLAS_FMA
    float wv=fF(hv2, z2, z1);
    float t2=fM(-tau1, wv);
    z1=fA(z1, t2);
    z2=fF(t2, hv2, z2);
#else
    float wv=fA(z1, fM(z2,hv2));
    float t2=fM(-tau1, wv);
    z1=fA(z1, t2);
    z2=fA(z2, fM(hv2,t2));
#endif
  }
  vout[0]=z0; vout[1]=z1; vout[2]=z2;
}

struct KP {
  const float* x; const float* rs; const float* rl;
  const float *w1,*b1,*g1,*be1,*m1,*v1;
  const float *w2,*b2,*g2,*be2,*m2,*v2;
  const float *w3,*b3,*g3,*be3,*m3,*v3;
  const float *w4,*b4,*g4,*be4,*m4,*v4;
  float* out;
};

// ws region A: per-point idx record, 128 u16 = 256 B.
// [0..63]=idxL, [64..95]=idxS, [96]=cl, [97]=cs.
#define WS_STRIDE 128

// ---- Kernel 1: wave-per-point ballot scan (R7-validated membership order) ----
__global__ __launch_bounds__(64) void scan_kernel(const float* __restrict__ x,
                                                  const float* __restrict__ rsp,
                                                  const float* __restrict__ rlp,
                                                  unsigned short* __restrict__ ws){
  const int lane=threadIdx.x;
  const int pt=blockIdx.x;
  const int b=pt>>12, n=pt&4095;
  const float* P=x+(size_t)b*(4096*3);
  const double rds=rint((double)rsp[0]*1e7)/1e7;
  const double rdl=rint((double)rlp[0]*1e7)/1e7;
  const float rr_s=(float)(rds*rds);
  const float rr_l=(float)(rdl*rdl);
  const float px=P[3*n], py=P[3*n+1], pz=P[3*n+2];
  const float sqn=fA(fA(fM(px,px),fM(py,py)),fM(pz,pz));
  unsigned short* w=ws+(size_t)pt*WS_STRIDE;
  int cs=0, cl=0;
  for (int c=0;c<64;++c){
    int j=c*64+lane;
    float qx=P[3*j], qy=P[3*j+1], qz=P[3*j+2];
    float sqj=fA(fA(fM(qx,qx),fM(qy,qy)),fM(qz,qz));
    float dot=fA(fA(fM(px,qx),fM(py,qy)),fM(pz,qz));
    float d2=fSb(fA(sqn,sqj), fM(2.0f,dot));
    bool pl=!(d2>rr_l);
    bool ps=!(d2>rr_s);
    unsigned long long bl=__ballot(pl);
    unsigned long long bs=__ballot(ps);
    unsigned long long ltm=(1ull<<lane)-1ull;
    int posl=cl+__popcll(bl&ltm);
    int poss=cs+__popcll(bs&ltm);
    if (pl&&posl<64) w[posl]=(unsigned short)j;
    if (ps&&poss<32) w[64+poss]=(unsigned short)j;
    cl+=__popcll(bl); if(cl>64) cl=64;
    cs+=__popcll(bs); if(cs>32) cs=32;
    if (cs>=32&&cl>=64) break;          // wave-uniform
  }
  if (lane==0){ w[96]=(unsigned short)cl; w[97]=(unsigned short)cs; }
}

// ---- Kernel 2: moments — one point per lane; coords + ws idx staged in LDS ----
__global__ __launch_bounds__(64) void moments_kernel(const float* __restrict__ x,
                                                     const unsigned short* __restrict__ ws,
                                                     float* __restrict__ covB){
  __shared__ float sP[4096*3];            // 48 KB batch coords
  __shared__ unsigned int sWu[64*65];     // 64 records x 64 dwords, row-padded to 65
  const int lane=threadIdx.x;
  const int base=blockIdx.x*64;
  const int b=base>>12;
  const float* P=x+(size_t)b*(4096*3);
  {
    const float4* src=(const float4*)P;
    float4* dst=(float4*)sP;
    for (int i=lane;i<4096*3/4;i+=64) dst[i]=src[i];
  }
  {
    const unsigned int* wsrc=(const unsigned int*)(ws+(size_t)base*WS_STRIDE);
    for (int i=lane;i<64*64;i+=64){
      int row=i>>6, col=i&63;
      sWu[row*65+col]=wsrc[i];
    }
  }
  __syncthreads();

  const unsigned short* sW16=(const unsigned short*)sWu;
  const int rbase=lane*130;
  const int cln=sW16[rbase+96], csn=sW16[rbase+97];
  const int j0l=sW16[rbase+0],  j0s=sW16[rbase+64];

  float ssx=0.0f,ssy=0.0f,ssz=0.0f, slx=0.0f,sly=0.0f,slz=0.0f;
#pragma unroll 16
  for (int k=0;k<32;++k){
    int idx=(k<csn)?(int)sW16[rbase+64+k]:j0s;
    ssx=fA(ssx,sP[3*idx]); ssy=fA(ssy,sP[3*idx+1]); ssz=fA(ssz,sP[3*idx+2]);
  }
#pragma unroll 16
  for (int k=0;k<64;++k){
    int idx=(k<cln)?(int)sW16[rbase+k]:j0l;
    slx=fA(slx,sP[3*idx]); sly=fA(sly,sP[3*idx+1]); slz=fA(slz,sP[3*idx+2]);
  }
  const float msx=fDv(ssx,32.0f), msy=fDv(ssy,32.0f), msz=fDv(ssz,32.0f);
  const float mlx=fDv(slx,64.0f), mly=fDv(sly,64.0f), mlz=fDv(slz,64.0f);

  float sc0=0,sc1=0,sc2=0,sc3=0,sc4=0,sc5=0;
#pragma unroll 16
  for (int k=0;k<32;++k){
    int idx=(k<csn)?(int)sW16[rbase+64+k]:j0s;
    float cx=fSb(sP[3*idx],msx), cy=fSb(sP[3*idx+1],msy), cz=fSb(sP[3*idx+2],msz);
    sc0=fA(sc0,fM(cx,cx)); sc1=fA(sc1,fM(cy,cx)); sc2=fA(sc2,fM(cz,cx));
    sc3=fA(sc3,fM(cy,cy)); sc4=fA(sc4,fM(cz,cy)); sc5=fA(sc5,fM(cz,cz));
  }
  float lc0=0,lc1=0,lc2=0,lc3=0,lc4=0,lc5=0;
#pragma unroll 16
  for (int k=0;k<64;++k){
    int idx=(k<cln)?(int)sW16[rbase+k]:j0l;
    float cx=fSb(sP[3*idx],mlx), cy=fSb(sP[3*idx+1],mly), cz=fSb(sP[3*idx+2],mlz);
    lc0=fA(lc0,fM(cx,cx)); lc1=fA(lc1,fM(cy,cx)); lc2=fA(lc2,fM(cz,cx));
    lc3=fA(lc3,fM(cy,cy)); lc4=fA(lc4,fM(cz,cy)); lc5=fA(lc5,fM(cz,cz));
  }

  float* cb=covB+(size_t)(base+lane)*12;
  cb[0]=sc0; cb[1]=sc1; cb[2]=sc2; cb[3]=sc3; cb[4]=sc4; cb[5]=sc5;
  cb[6]=lc0; cb[7]=lc1; cb[8]=lc2; cb[9]=lc3; cb[10]=lc4; cb[11]=lc5;
}

// ---- Kernel 3: eig (2-lane redundancy, 32 eigs/wave) + fused curvature/MLP ----
__global__ __launch_bounds__(64) void eigmlp_kernel(KP kp, const float* __restrict__ covB){
  __shared__ float sN[32][3];
  const int lane=threadIdx.x;
  const int g=lane>>1;                    // group 0..31
  const int t=blockIdx.x*32+g;            // task id < 2*BN
  const int p=t>>1, which=t&1;            // which: 0=small, 1=large
  const float* cb=covB+(size_t)p*12+which*6;
  float v[3];
  eig3_smallest(cb[0],cb[1],cb[2],cb[3],cb[4],cb[5],v);
  if ((lane&1)==0){ sN[g][0]=v[0]; sN[g][1]=v[1]; sN[g][2]=v[2]; }
  __syncthreads();

  if (lane<16){
    const int pt=blockIdx.x*16+lane;
    const float* sn=sN[2*lane];           // which=0 (small)
    const float* ln=sN[2*lane+1];         // which=1 (large)
    float dx=fM(fSb(sn[0],ln[0]),0.5f);
    float dy=fM(fSb(sn[1],ln[1]),0.5f);
    float dz=fM(fSb(sn[2],ln[2]),0.5f);
    float curv=fQ(fA(fA(fM(dx,dx),fM(dy,dy)),fM(dz,dz)));

    float h1[16];
#pragma unroll
    for (int j=0;j<16;++j){
      float a0=fA(fM(kp.w1[j],curv), kp.b1[j]);
      a0=fA(fM(fDv(fSb(a0,kp.m1[j]), fQ(fA(kp.v1[j],1e-5f))), kp.g1[j]), kp.be1[j]);
      h1[j]=fmaxf(a0,0.0f);
    }
    float h2[32];
#pragma unroll
    for (int j=0;j<32;++j){
      float a0=0.0f;
#pragma unroll
      for (int k=0;k<16;++k) a0=fF(h1[k], kp.w2[j*16+k], a0);
      a0=fA(a0, kp.b2[j]);
      a0=fA(fM(fDv(fSb(a0,kp.m2[j]), fQ(fA(kp.v2[j],1e-5f))), kp.g2[j]), kp.be2[j]);
      h2[j]=fmaxf(a0,0.0f);
    }
    float h3[16];
#pragma unroll
    for (int j=0;j<16;++j){
      float a0=0.0f;
#pragma unroll
      for (int k=0;k<32;++k) a0=fF(h2[k], kp.w3[j*32+k], a0);
      a0=fA(a0, kp.b3[j]);
      a0=fA(fM(fDv(fSb(a0,kp.m3[j]), fQ(fA(kp.v3[j],1e-5f))), kp.g3[j]), kp.be3[j]);
      h3[j]=fmaxf(a0,0.0f);
    }
    float o=0.0f;
#pragma unroll
    for (int k=0;k<16;++k) o=fF(h3[k], kp.w4[k], o);
    o=fA(o, kp.b4[0]);
    o=fA(fM(fDv(fSb(o,kp.m4[0]), fQ(fA(kp.v4[0],1e-5f))), kp.g4[0]), kp.be4[0]);
    kp.out[pt]=o;
  }
}

// ---- Fallback: R8 monolithic kernel (used only if ws is too small) ----
__global__ __launch_bounds__(256) void freq_kernel(KP kp){
  __shared__ float sP[4096*3];
  __shared__ float sSq[4096];
  __shared__ unsigned short sIdxL[64][66];
  __shared__ unsigned short sIdxS[64][34];
  __shared__ unsigned char sCntL[64], sCntS[64];
  const int tid=threadIdx.x;
  const int lane=tid&63, wid=tid>>6;
  const int b=blockIdx.x>>6;
  const int n0=(blockIdx.x&63)*64;
  const float* P=kp.x+(size_t)b*(4096*3);
  for (int i=tid;i<4096*3;i+=256) sP[i]=P[i];
  for (int j=tid;j<4096;j+=256){
    float qx=P[3*j],qy=P[3*j+1],qz=P[3*j+2];
    sSq[j]=fA(fA(fM(qx,qx),fM(qy,qy)),fM(qz,qz));
  }
  __syncthreads();
  const double rds=rint((double)kp.rs[0]*1e7)/1e7;
  const double rdl=rint((double)kp.rl[0]*1e7)/1e7;
  const float rr_s=(float)(rds*rds);
  const float rr_l=(float)(rdl*rdl);
  for (int pi=0; pi<16; ++pi){
    const int pl_i=wid*16+pi;
    const int n=n0+pl_i;
    const float px=sP[3*n], py=sP[3*n+1], pz=sP[3*n+2];
    const float sqn=sSq[n];
    int cs=0, cl=0;
    for (int c=0;c<64;++c){
      int j=c*64+lane;
      float dot=fA(fA(fM(px,sP[3*j]),fM(py,sP[3*j+1])),fM(pz,sP[3*j+2]));
      float d2=fSb(fA(sqn,sSq[j]), fM(2.0f,dot));
      bool pl_=!(d2>rr_l);
      bool ps_=!(d2>rr_s);
      unsigned long long bl=__ballot(pl_);
      unsigned long long bs=__ballot(ps_);
      unsigned long long ltm=(1ull<<lane)-1ull;
      int posl=cl+__popcll(bl&ltm);
      int poss=cs+__popcll(bs&ltm);
      if (pl_&&posl<64) sIdxL[pl_i][posl]=(unsigned short)j;
      if (ps_&&poss<32) sIdxS[pl_i][poss]=(unsigned short)j;
      cl+=__popcll(bl); if(cl>64) cl=64;
      cs+=__popcll(bs); if(cs>32) cs=32;
      if (cs>=32&&cl>=64) break;
    }
    if (lane==0){ sCntL[pl_i]=(unsigned char)cl; sCntS[pl_i]=(unsigned char)cs; }
  }
  __syncthreads();
  if (lane<16){
    const int pl_i=wid*16+lane;
    const int ptg=blockIdx.x*64+pl_i;
    const int csn=sCntS[pl_i], cln=sCntL[pl_i];
    const int j0s=sIdxS[pl_i][0], j0l=sIdxL[pl_i][0];
    float ssx=0.0f,ssy=0.0f,ssz=0.0f, slx=0.0f,sly=0.0f,slz=0.0f;
    for (int k=0;k<32;++k){
      int idx=(k<csn)?(int)sIdxS[pl_i][k]:j0s;
      ssx=fA(ssx,sP[3*idx]); ssy=fA(ssy,sP[3*idx+1]); ssz=fA(ssz,sP[3*idx+2]);
    }
    for (int k=0;k<64;++k){
      int idx=(k<cln)?(int)sIdxL[pl_i][k]:j0l;
      slx=fA(slx,sP[3*idx]); sly=fA(sly,sP[3*idx+1]); slz=fA(slz,sP[3*idx+2]);
    }
    const float msx=fDv(ssx,32.0f), msy=fDv(ssy,32.0f), msz=fDv(ssz,32.0f);
    const float mlx=fDv(slx,64.0f), mly=fDv(sly,64.0f), mlz=fDv(slz,64.0f);
    float sc0=0,sc1=0,sc2=0,sc3=0,sc4=0,sc5=0;
    for (int k=0;k<32;++k){
      int idx=(k<csn)?(int)sIdxS[pl_i][k]:j0s;
      float cx=fSb(sP[3*idx],msx), cy=fSb(sP[3*idx+1],msy), cz=fSb(sP[3*idx+2],msz);
      sc0=fA(sc0,fM(cx,cx)); sc1=fA(sc1,fM(cy,cx)); sc2=fA(sc2,fM(cz,cx));
      sc3=fA(sc3,fM(cy,cy)); sc4=fA(sc4,fM(cz,cy)); sc5=fA(sc5,fM(cz,cz));
    }
    float lc0=0,lc1=0,lc2=0,lc3=0,lc4=0,lc5=0;
    for (int k=0;k<64;++k){
      int idx=(k<cln)?(int)sIdxL[pl_i][k]:j0l;
      float cx=fSb(sP[3*idx],mlx), cy=fSb(sP[3*idx+1],mly), cz=fSb(sP[3*idx+2],mlz);
      lc0=fA(lc0,fM(cx,cx)); lc1=fA(lc1,fM(cy,cx)); lc2=fA(lc2,fM(cz,cx));
      lc3=fA(lc3,fM(cy,cy)); lc4=fA(lc4,fM(cz,cy)); lc5=fA(lc5,fM(cz,cz));
    }
    float snv[3], lnv[3];
    eig3_smallest(sc0,sc1,sc2,sc3,sc4,sc5, snv);
    eig3_smallest(lc0,lc1,lc2,lc3,lc4,lc5, lnv);
    float dx=fM(fSb(snv[0],lnv[0]),0.5f);
    float dy=fM(fSb(snv[1],lnv[1]),0.5f);
    float dz=fM(fSb(snv[2],lnv[2]),0.5f);
    float curv=fQ(fA(fA(fM(dx,dx),fM(dy,dy)),fM(dz,dz)));
    float h1[16];
#pragma unroll
    for (int j=0;j<16;++j){
      float a0=fA(fM(kp.w1[j],curv), kp.b1[j]);
      a0=fA(fM(fDv(fSb(a0,kp.m1[j]), fQ(fA(kp.v1[j],1e-5f))), kp.g1[j]), kp.be1[j]);
      h1[j]=fmaxf(a0,0.0f);
    }
    float h2[32];
#pragma unroll
    for (int j=0;j<32;++j){
      float a0=0.0f;
#pragma unroll
      for (int k=0;k<16;++k) a0=fF(h1[k], kp.w2[j*16+k], a0);
      a0=fA(a0, kp.b2[j]);
      a0=fA(fM(fDv(fSb(a0,kp.m2[j]), fQ(fA(kp.v2[j],1e-5f))), kp.g2[j]), kp.be2[j]);
      h2[j]=fmaxf(a0,0.0f);
    }
    float h3[16];
#pragma unroll
    for (int j=0;j<16;++j){
      float a0=0.0f;
#pragma unroll
      for (int k=0;k<32;++k) a0=fF(h2[k], kp.w3[j*32+k], a0);
      a0=fA(a0, kp.b3[j]);
      a0=fA(fM(fDv(fSb(a0,kp.m3[j]), fQ(fA(kp.v3[j],1e-5f))), kp.g3[j]), kp.be3[j]);
      h3[j]=fmaxf(a0,0.0f);
    }
    float o=0.0f;
#pragma unroll
    for (int k=0;k<16;++k) o=fF(h3[k], kp.w4[k], o);
    o=fA(o, kp.b4[0]);
    o=fA(fM(fDv(fSb(o,kp.m4[0]), fQ(fA(kp.v4[0],1e-5f))), kp.g4[0]), kp.be4[0]);
    kp.out[ptg]=o;
  }
}

extern "C" void kernel_launch(void* const* d_in, const int* in_sizes, int n_in,
                              void* d_out, int out_size, void* d_ws, size_t ws_size,
                              hipStream_t stream){
  (void)n_in; (void)out_size;
  KP kp;
  kp.x  =(const float*)d_in[0];
  kp.rs =(const float*)d_in[1];
  kp.rl =(const float*)d_in[2];
  kp.w1 =(const float*)d_in[3];  kp.b1 =(const float*)d_in[4];  kp.g1 =(const float*)d_in[5];
  kp.be1=(const float*)d_in[6];  kp.m1 =(const float*)d_in[7];  kp.v1 =(const float*)d_in[8];
  kp.w2 =(const float*)d_in[9];  kp.b2 =(const float*)d_in[10]; kp.g2 =(const float*)d_in[11];
  kp.be2=(const float*)d_in[12]; kp.m2 =(const float*)d_in[13]; kp.v2 =(const float*)d_in[14];
  kp.w3 =(const float*)d_in[15]; kp.b3 =(const float*)d_in[16]; kp.g3 =(const float*)d_in[17];
  kp.be3=(const float*)d_in[18]; kp.m3 =(const float*)d_in[19]; kp.v3 =(const float*)d_in[20];
  kp.w4 =(const float*)d_in[21]; kp.b4 =(const float*)d_in[22]; kp.g4 =(const float*)d_in[23];
  kp.be4=(const float*)d_in[24]; kp.m4 =(const float*)d_in[25]; kp.v4 =(const float*)d_in[26];
  kp.out=(float*)d_out;
  const int BN=in_sizes[0]/3;               // B*N points
  // ws: A = idx records (BN*256 B), B = cov (BN*12 f32)
  const size_t ws_need=(size_t)BN*(256+48);
  if (ws_size>=ws_need){
    unsigned short* wsA=(unsigned short*)d_ws;
    float* covB=(float*)((char*)d_ws + (size_t)BN*256);
    scan_kernel<<<BN, 64, 0, stream>>>(kp.x, kp.rs, kp.rl, wsA);
    moments_kernel<<<BN/64, 64, 0, stream>>>(kp.x, wsA, covB);
    eigmlp_kernel<<<BN/16, 64, 0, stream>>>(kp, covB);
  } else {
    freq_kernel<<<BN/64, 256, 0, stream>>>(kp);
  }
}